// Round 9
// baseline (140.792 us; speedup 1.0000x reference)
//
#include <hip/hip_runtime.h>
#include <hip/hip_bf16.h>
#include <stdint.h>

#define S_TOK 3072
#define E_DIM 1280
#define H_NUM 20
#define D_HEAD 64
#define NSEG 16

typedef __attribute__((ext_vector_type(8))) short short8;
typedef __attribute__((ext_vector_type(4))) float f32x4;

__device__ __forceinline__ unsigned short f2bf(float f){
  union { float f; unsigned int i; } u; u.f = f;
  unsigned int r = u.i + 0x7FFFu + ((u.i >> 16) & 1u);
  return (unsigned short)(r >> 16);
}

__device__ __forceinline__ void gload_lds16(const void* g, void* l){
  __builtin_amdgcn_global_load_lds((__attribute__((address_space(1))) void*)(g),
                                   (__attribute__((address_space(3))) void*)(l), 16, 0, 0);
}

// ---------------- all f32 -> bf16 conversions in one launch ----------------
__global__ void cvt_all(const float* __restrict__ hs,
                        const float* __restrict__ w0, const float* __restrict__ w1,
                        const float* __restrict__ w2, const float* __restrict__ w3,
                        unsigned short* __restrict__ hsb,
                        unsigned short* __restrict__ dqkv, unsigned short* __restrict__ dob,
                        int nHS4, int nW4){
  int i = blockIdx.x * blockDim.x + threadIdx.x;
  const float* src;
  unsigned short* dst;
  size_t sj, dj;
  if (i < nHS4){
    src = hs; dst = hsb; sj = i; dj = i;
  } else {
    int t = i - nHS4;
    int w = t / nW4;
    if (w >= 4) return;
    int j = t - w * nW4;
    src = (w == 0) ? w0 : (w == 1) ? w1 : (w == 2) ? w2 : w3;
    sj = j;
    if (w < 3){ dst = dqkv; dj = (size_t)w * nW4 + j; }
    else      { dst = dob;  dj = j; }
  }
  float4 v = reinterpret_cast<const float4*>(src)[sj];
  ushort4 o;
  o.x = f2bf(v.x); o.y = f2bf(v.y); o.z = f2bf(v.z); o.w = f2bf(v.w);
  reinterpret_cast<ushort4*>(dst)[dj] = o;
}

// ------------- GEMM, split-pipe: A via LDS, B direct from global -------------
// C = A[M,K] @ B[N,K]^T, bf16 in, f32 acc. BM=BN=128, 4 waves, wave-tile
// 64x64 (MR=NR=4). A staged in LDS ring-3 (BK=64, 16 KB/slot, swizzled,
// stage t+2 at END of iter t; entry vmcnt(4) = tile t complete). B fragments
// are global_load_dwordx4 straight from L1/L2 (16 lanes x 128 B contiguous
// per fragment) -> LDS pipe carries only A, VMEM pipe carries B, they overlap.
// 720 blocks QKV / 240 out-proj; 3 blocks/CU (launch_bounds 256,3).
// MODE 0: scatter q/k/v bf16 [H][S][D] via LDS-staged coalesced epilogue.
// MODE 1: f32 out [S][E] + bias, direct stores.
template<int MODE>
__global__ __launch_bounds__(256, 3) void gemm_bg(
    const unsigned short* __restrict__ A,
    const unsigned short* __restrict__ Bp,
    const float* __restrict__ bias0,
    const float* __restrict__ bias1,
    unsigned short* __restrict__ Oq,
    unsigned short* __restrict__ Ok,
    unsigned short* __restrict__ Ov,
    float* __restrict__ Of,
    int M, int N, int K)
{
  __shared__ __align__(16) unsigned short SH[3 * 8192];   // 48 KB: 3 x A[128][64]

  const int nbm = M >> 7;
  const int bm = blockIdx.x % nbm;       // column-major: same-bn blocks adjacent
  const int bn = blockIdx.x / nbm;
  const int row0 = bm << 7;
  const int col0 = bn << 7;

  const int tid  = threadIdx.x;
  const int lane = tid & 63;
  const int w    = tid >> 6;
  const int wm   = w >> 1;               // 0..1
  const int wn   = w & 1;                // 0..1

  const f32x4 fz = {0.f, 0.f, 0.f, 0.f};
  f32x4 acc[4][4];
#pragma unroll
  for (int m = 0; m < 4; ++m)
#pragma unroll
    for (int n = 0; n < 4; ++n) acc[m][n] = fz;

  // per-thread B fragment base: row = col0 + wn*64 + (lane&15), k-offset (lane>>4)*8
  const unsigned short* Bbase = Bp + (size_t)(col0 + wn * 64 + (lane & 15)) * K + (lane >> 4) * 8;

  // A staging: 1024 16B-slots (128 rows x 8 slots); phys slot p of row r holds
  // k-chunk p ^ (r&7)  (2-way bank aliasing max on frag reads = free)
  auto stage = [&](int slot, int t){
    unsigned short* dstb = SH + slot * 8192;
    const int k0 = t << 6;
#pragma unroll
    for (int i = 0; i < 4; ++i){
      int s = i * 256 + tid;
      int r = s >> 3, p = s & 7;
      int ks = p ^ (r & 7);
      gload_lds16(A + (size_t)(row0 + r) * K + k0 + ks * 8, dstb + s * 8);
    }
  };

  const int nk = K >> 6;                 // 20
  stage(0, 0);
  stage(1, 1);
  for (int t = 0; t < nk; ++t){
    if (t == nk - 1) asm volatile("s_waitcnt vmcnt(0)" ::: "memory");
    else             asm volatile("s_waitcnt vmcnt(4)" ::: "memory");
    __builtin_amdgcn_s_barrier();
    const unsigned short* As = SH + (t % 3) * 8192;
#pragma unroll
    for (int kk = 0; kk < 2; ++kk){
      short8 bf[4], af[4];
#pragma unroll
      for (int n = 0; n < 4; ++n)
        bf[n] = *reinterpret_cast<const short8*>(Bbase + (size_t)n * 16 * K + t * 64 + kk * 32);
#pragma unroll
      for (int m = 0; m < 4; ++m){
        int ra = wm * 64 + m * 16 + (lane & 15);
        int slot = kk * 4 + (lane >> 4);
        af[m] = *reinterpret_cast<const short8*>(&As[ra * 64 + ((slot ^ (ra & 7))) * 8]);
      }
      __builtin_amdgcn_s_setprio(1);
#pragma unroll
      for (int m = 0; m < 4; ++m)
#pragma unroll
        for (int n = 0; n < 4; ++n)
          acc[m][n] = __builtin_amdgcn_mfma_f32_16x16x32_bf16(af[m], bf[n], acc[m][n], 0, 0, 0);
      __builtin_amdgcn_s_setprio(0);
    }
    // issue next prefetch LAST so in-iter B-waits don't drain it
    if (t + 2 < nk) stage((t + 2) % 3, t + 2);
  }
  __syncthreads();   // all LDS reads done before epilogue reuses SH

  if (MODE == 0){
    // coalesced scatter epilogue: two 64-row phases staged in LDS
    unsigned short* Cs = SH;
    const int CSTR = 136;                  // 64 x 136 = 8704 shorts <= 24576
    const int mat = col0 / E_DIM;          // no q/k/v straddle (1280 % 128 == 0)
    const int cc0 = col0 - mat * E_DIM;
    unsigned short* dst = (mat == 0) ? Oq : ((mat == 1) ? Ok : Ov);
    float bb[4];
#pragma unroll
    for (int n = 0; n < 4; ++n){
      int cc = cc0 + wn * 64 + n * 16 + (lane & 15);
      bb[n] = (mat == 0) ? bias0[cc] : (mat == 2 ? bias1[cc] : 0.0f);
    }
#pragma unroll
    for (int ph = 0; ph < 2; ++ph){
      if (wm == ph){
#pragma unroll
        for (int m = 0; m < 4; ++m)
#pragma unroll
          for (int n = 0; n < 4; ++n)
#pragma unroll
            for (int j = 0; j < 4; ++j){
              int rr = m * 16 + (lane >> 4) * 4 + j;      // 0..63
              int c  = wn * 64 + n * 16 + (lane & 15);    // 0..127
              Cs[rr * CSTR + c] = f2bf(acc[m][n][j] + bb[n]);
            }
      }
      __syncthreads();
#pragma unroll
      for (int i = 0; i < 4; ++i){
        int tk  = i * 256 + tid;        // 1024 tasks = 2 head-panels x 64r x 8sl
        int p   = tk >> 9;
        int idx = tk & 511;
        int rr  = idx >> 3, sq = idx & 7;
        short8 vv = *reinterpret_cast<const short8*>(&Cs[rr * CSTR + p * 64 + sq * 8]);
        int gr = row0 + ph * 64 + rr;
        int hh = (cc0 >> 6) + p;
        *reinterpret_cast<short8*>(&dst[((size_t)hh * S_TOK + gr) * D_HEAD + sq * 8]) = vv;
      }
      __syncthreads();
    }
  } else {
#pragma unroll
    for (int m = 0; m < 4; ++m)
#pragma unroll
      for (int n = 0; n < 4; ++n){
        int c = col0 + wn * 64 + n * 16 + (lane & 15);
        float b = bias0[c];
#pragma unroll
        for (int j = 0; j < 4; ++j){
          int r = row0 + wm * 64 + m * 16 + (lane >> 4) * 4 + j;
          Of[(size_t)r * E_DIM + c] = acc[m][n][j] + b;
        }
      }
  }
}

// ---------------- block-diagonal attention ----------------
// grid = H*NSEG*3 blocks of 256 threads (4 waves x 16 Q-rows = 64 rows/block).
#define VSTR 200
#define PSTR 72
__global__ __launch_bounds__(256, 3) void attn_kernel(
    const unsigned short* __restrict__ Q,
    const unsigned short* __restrict__ Kb,
    const unsigned short* __restrict__ V,
    const int* __restrict__ cu,
    unsigned short* __restrict__ O)
{
  __shared__ __align__(16) unsigned short Vt[64*VSTR];     // [d][k-row]
  __shared__ __align__(16) unsigned short Pw[4][16][PSTR]; // per-wave scratch

  const int bid  = blockIdx.x;
  const int unit = bid / 3;
  const int third= bid - unit*3;
  const int h    = unit >> 4;
  const int seg  = unit & 15;
  const int s0   = cu[seg];
  const int L    = cu[seg + 1] - s0;
  if (L <= 0) return;

  const int tid  = threadIdx.x;
  const int lane = tid & 63;
  const int w    = tid >> 6;
  const int row0g = third*64 + w*16;

  const unsigned short* qh = Q  + (size_t)h * S_TOK * D_HEAD;
  const unsigned short* kh = Kb + (size_t)h * S_TOK * D_HEAD;
  const unsigned short* vh = V  + (size_t)h * S_TOK * D_HEAD;

#pragma unroll
  for (int i = 0; i < 6; ++i){
    int task = i*256 + tid;            // 1536 tasks = 192 rows x 8 d-groups
    int sr   = task % 192;
    int grp  = task / 192;
    int svr  = s0 + (sr < L ? sr : L - 1);
    short8 vv = *reinterpret_cast<const short8*>(vh + (size_t)svr*64 + grp*8);
#pragma unroll
    for (int j = 0; j < 8; ++j) Vt[(grp*8 + j)*VSTR + sr] = (unsigned short)vv[j];
  }

  short8 qf[2];
#pragma unroll
  for (int kk = 0; kk < 2; ++kk){
    int r  = row0g + (lane & 15);
    int sr = s0 + (r < L ? r : L - 1);
    qf[kk] = *reinterpret_cast<const short8*>(qh + (size_t)sr*64 + kk*32 + (lane >> 4)*8);
  }

  __syncthreads();

  const f32x4 fz = {0.f, 0.f, 0.f, 0.f};
  const float SCL = 0.125f * 1.44269504088896f;

  f32x4 sacc[12];
#pragma unroll
  for (int nt = 0; nt < 12; ++nt) sacc[nt] = fz;

#pragma unroll
  for (int nt = 0; nt < 12; ++nt){
    int rb = nt*16 + (lane & 15);
    int sr = s0 + (rb < L ? rb : L - 1);
    const unsigned short* kr = kh + (size_t)sr*64 + (lane >> 4)*8;
    short8 kf0 = *reinterpret_cast<const short8*>(kr);
    short8 kf1 = *reinterpret_cast<const short8*>(kr + 32);
    sacc[nt] = __builtin_amdgcn_mfma_f32_16x16x32_bf16(qf[0], kf0, sacc[nt], 0, 0, 0);
    sacc[nt] = __builtin_amdgcn_mfma_f32_16x16x32_bf16(qf[1], kf1, sacc[nt], 0, 0, 0);
  }

  float rinv[4];
#pragma unroll
  for (int j = 0; j < 4; ++j){
    float mx = -1e30f;
#pragma unroll
    for (int nt = 0; nt < 12; ++nt){
      int c = nt*16 + (lane & 15);
      float vv = (c < L) ? sacc[nt][j] : -1e30f;
      sacc[nt][j] = vv;
      mx = fmaxf(mx, vv);
    }
    mx = fmaxf(mx, __shfl_xor(mx, 1, 64));
    mx = fmaxf(mx, __shfl_xor(mx, 2, 64));
    mx = fmaxf(mx, __shfl_xor(mx, 4, 64));
    mx = fmaxf(mx, __shfl_xor(mx, 8, 64));
    float sum = 0.f;
#pragma unroll
    for (int nt = 0; nt < 12; ++nt){
      float pp = exp2f((sacc[nt][j] - mx) * SCL);
      sacc[nt][j] = pp;
      sum += pp;
    }
    sum += __shfl_xor(sum, 1, 64);
    sum += __shfl_xor(sum, 2, 64);
    sum += __shfl_xor(sum, 4, 64);
    sum += __shfl_xor(sum, 8, 64);
    rinv[j] = 1.0f / sum;
  }

  f32x4 oacc[4];
#pragma unroll
  for (int nt = 0; nt < 4; ++nt) oacc[nt] = fz;

#pragma unroll
  for (int kk = 0; kk < 6; ++kk){
#pragma unroll
    for (int ntl = 0; ntl < 2; ++ntl){
      int nt = kk*2 + ntl;
#pragma unroll
      for (int j = 0; j < 4; ++j)
        Pw[w][(lane >> 4)*4 + j][ntl*16 + (lane & 15)] = f2bf(sacc[nt][j]);
    }
    short8 pf = *reinterpret_cast<const short8*>(&Pw[w][lane & 15][(lane >> 4)*8]);
#pragma unroll
    for (int nt4 = 0; nt4 < 4; ++nt4){
      int dcol = nt4*16 + (lane & 15);
      short8 vf = *reinterpret_cast<const short8*>(&Vt[dcol*VSTR + kk*32 + (lane >> 4)*8]);
      oacc[nt4] = __builtin_amdgcn_mfma_f32_16x16x32_bf16(pf, vf, oacc[nt4], 0, 0, 0);
    }
  }

#pragma unroll
  for (int nt4 = 0; nt4 < 4; ++nt4)
#pragma unroll
    for (int j = 0; j < 4; ++j)
      Pw[w][(lane >> 4)*4 + j][nt4*16 + (lane & 15)] = f2bf(oacc[nt4][j] * rinv[j]);

  {
    int r = lane >> 2;
    int gr = row0g + r;
    if (gr < L){
#pragma unroll
      for (int part = 0; part < 2; ++part){
        int c0 = (lane & 3)*16 + part*8;
        short8 vv = *reinterpret_cast<const short8*>(&Pw[w][r][c0]);
        *reinterpret_cast<short8*>(&O[(size_t)(s0 + gr) * E_DIM + h*64 + c0]) = vv;
      }
    }
  }
}

// ---------------- host launch ----------------
extern "C" void kernel_launch(void* const* d_in, const int* in_sizes, int n_in,
                              void* d_out, int out_size, void* d_ws, size_t ws_size,
                              hipStream_t stream)
{
  const float* hs = (const float*)d_in[0];
  const float* Wq = (const float*)d_in[1];
  const float* bq = (const float*)d_in[2];
  const float* Wk = (const float*)d_in[3];
  const float* Wv = (const float*)d_in[4];
  const float* bv = (const float*)d_in[5];
  const float* Wo = (const float*)d_in[6];
  const float* bo = (const float*)d_in[7];
  const int*   cu = (const int*)d_in[8];
  float* out = (float*)d_out;

  unsigned short* p = (unsigned short*)d_ws;
  unsigned short* hsb  = p; p += (size_t)S_TOK * E_DIM;
  unsigned short* wqkv = p; p += (size_t)3 * E_DIM * E_DIM;
  unsigned short* wob  = p; p += (size_t)E_DIM * E_DIM;
  unsigned short* qb   = p; p += (size_t)S_TOK * E_DIM;
  unsigned short* kb   = p; p += (size_t)S_TOK * E_DIM;
  unsigned short* vb   = p; p += (size_t)S_TOK * E_DIM;
  unsigned short* aob  = p; p += (size_t)S_TOK * E_DIM;

  const int nHS4 = S_TOK * E_DIM / 4;
  const int nW4  = E_DIM * E_DIM / 4;
  const int nCvt = nHS4 + 4 * nW4;
  cvt_all<<<(nCvt + 255) / 256, 256, 0, stream>>>(hs, Wq, Wk, Wv, Wo, hsb, wqkv, wob, nHS4, nW4);

  // QKV: 24 x 30 = 720 blocks of 256
  gemm_bg<0><<<(S_TOK/128) * (3*E_DIM/128), 256, 0, stream>>>(
      hsb, wqkv, bq, bv, qb, kb, vb, nullptr, S_TOK, 3*E_DIM, E_DIM);

  attn_kernel<<<H_NUM * NSEG * 3, 256, 0, stream>>>(qb, kb, vb, cu, aob);

  // out-proj: 24 x 10 = 240 blocks of 256
  gemm_bg<1><<<(S_TOK/128) * (E_DIM/128), 256, 0, stream>>>(
      aob, wob, bo, nullptr, nullptr, nullptr, nullptr, out, S_TOK, E_DIM, E_DIM);
}

// Round 10
// 102.208 us; speedup vs baseline: 1.3775x; 1.3775x over previous
//
#include <hip/hip_runtime.h>
#include <hip/hip_bf16.h>
#include <stdint.h>

#define S_TOK 3072
#define E_DIM 1280
#define H_NUM 20
#define D_HEAD 64
#define NSEG 16

typedef __attribute__((ext_vector_type(8))) short short8;
typedef __attribute__((ext_vector_type(4))) float f32x4;

__device__ __forceinline__ unsigned short f2bf(float f){
  union { float f; unsigned int i; } u; u.f = f;
  unsigned int r = u.i + 0x7FFFu + ((u.i >> 16) & 1u);
  return (unsigned short)(r >> 16);
}

__device__ __forceinline__ void gload_lds16(const void* g, void* l){
  __builtin_amdgcn_global_load_lds((__attribute__((address_space(1))) void*)(g),
                                   (__attribute__((address_space(3))) void*)(l), 16, 0, 0);
}

// ---------------- all f32 -> bf16 conversions in one launch ----------------
__global__ void cvt_all(const float* __restrict__ hs,
                        const float* __restrict__ w0, const float* __restrict__ w1,
                        const float* __restrict__ w2, const float* __restrict__ w3,
                        unsigned short* __restrict__ hsb,
                        unsigned short* __restrict__ dqkv, unsigned short* __restrict__ dob,
                        int nHS4, int nW4){
  int i = blockIdx.x * blockDim.x + threadIdx.x;
  const float* src;
  unsigned short* dst;
  size_t sj, dj;
  if (i < nHS4){
    src = hs; dst = hsb; sj = i; dj = i;
  } else {
    int t = i - nHS4;
    int w = t / nW4;
    if (w >= 4) return;
    int j = t - w * nW4;
    src = (w == 0) ? w0 : (w == 1) ? w1 : (w == 2) ? w2 : w3;
    sj = j;
    if (w < 3){ dst = dqkv; dj = (size_t)w * nW4 + j; }
    else      { dst = dob;  dj = j; }
  }
  float4 v = reinterpret_cast<const float4*>(src)[sj];
  ushort4 o;
  o.x = f2bf(v.x); o.y = f2bf(v.y); o.z = f2bf(v.z); o.w = f2bf(v.w);
  reinterpret_cast<ushort4*>(dst)[dj] = o;
}

// ---------------- pipelined GEMM: C = A[M,K] @ B[N,K]^T (bf16, f32 acc) -------
// r8 ring-4 structure + REGISTER DOUBLE-BUFFERED fragments: iter t reads
// frags(t+1) into the alternate bank while MFMA(t) runs on the current bank
// -> ds_read and MFMA have no data dependency -> LDS and MFMA pipes overlap
// (r8 serialized: lgkmcnt drained 1152 cyc of LDS before every 1242-cyc MFMA
// burst; measured 2770 cyc/iter = the sum). Entry vmcnt(4) after issuing
// stage(t+2) guarantees slot t+1 fully landed (cover ~1 iter); barrier makes
// it collective. Write-after-read: slot (t+2)&3 last read >=2 barriers ago.
// MODE 0: BM=BN=256, 8 waves (2x4), wave-tile 128x64, scatter q/k/v bf16.
// MODE 1: BM=BN=128, 4 waves (2x2), wave-tile 64x64, f32 out + bias.
template<int MODE, int BLOCK>
__global__ __launch_bounds__(BLOCK, 2) void gemm_pipe(
    const unsigned short* __restrict__ A,
    const unsigned short* __restrict__ Bp,
    const float* __restrict__ bias0,
    const float* __restrict__ bias1,
    unsigned short* __restrict__ Oq,
    unsigned short* __restrict__ Ok,
    unsigned short* __restrict__ Ov,
    float* __restrict__ Of,
    int M, int N, int K)
{
  constexpr int BM = (MODE == 0) ? 256 : 128;
  constexpr int BN = BM;
  constexpr int WN = (MODE == 0) ? 4 : 2;
  constexpr int WM = (BLOCK / 64) / WN;
  constexpr int MR = BM / WM / 16;      // 8 / 4
  constexpr int NR = BN / WN / 16;      // 4 / 4
  constexpr int SLOTSZ = (BM + BN) * 32;  // shorts per ring slot

  __shared__ __align__(16) unsigned short SH[4 * SLOTSZ];

  const int nbn = N >> (MODE == 0 ? 8 : 7);
  // supertile remap (4bm x 5bn chunks) for L2 locality; bijective since
  // nbm%4==0 and nbn%5==0 for both shapes here.
  const int sgn = nbn / 5;
  const int st = blockIdx.x / 20, ii = blockIdx.x % 20;
  const int bm = (st / sgn) * 4 + ii / 5;
  const int bn = (st % sgn) * 5 + ii % 5;
  const int row0 = bm * BM;
  const int col0 = bn * BN;

  const int tid  = threadIdx.x;
  const int lane = tid & 63;
  const int w    = tid >> 6;
  const int wm   = (MODE == 0) ? (w >> 2) : (w >> 1);
  const int wn   = (MODE == 0) ? (w & 3) : (w & 1);

  const f32x4 fz = {0.f, 0.f, 0.f, 0.f};
  f32x4 acc[MR][NR];
#pragma unroll
  for (int m = 0; m < MR; ++m)
#pragma unroll
    for (int n = 0; n < NR; ++n) acc[m][n] = fz;

  auto stage = [&](int slot, int t){
    unsigned short* base = SH + slot * SLOTSZ;
    const int k0 = t << 5;
#pragma unroll
    for (int i = 0; i < 4; ++i){
      int s = i * BLOCK + tid;
      int r = s >> 2, p = s & 3;
      int ks = p ^ ((r >> 1) & 3);
      const unsigned short* g = (r < BM)
          ? A  + (size_t)(row0 + r) * K + k0 + ks * 8
          : Bp + (size_t)(col0 + (r - BM)) * K + k0 + ks * 8;
      gload_lds16(g, base + s * 8);
    }
  };

  auto read_frags = [&](int u, short8* af, short8* bf){
    const unsigned short* As = SH + (u & 3) * SLOTSZ;
    const unsigned short* Bs = As + BM * 32;
#pragma unroll
    for (int n = 0; n < NR; ++n){
      int rb = wn * (BN / WN) + n * 16 + (lane & 15);
      bf[n] = *reinterpret_cast<const short8*>(&Bs[rb * 32 + (((lane >> 4) ^ ((rb >> 1) & 3))) * 8]);
    }
#pragma unroll
    for (int m = 0; m < MR; ++m){
      int ra = wm * (BM / WM) + m * 16 + (lane & 15);
      af[m] = *reinterpret_cast<const short8*>(&As[ra * 32 + (((lane >> 4) ^ ((ra >> 1) & 3))) * 8]);
    }
  };

  auto do_mfma = [&](const short8* af, const short8* bf){
    __builtin_amdgcn_s_setprio(1);
#pragma unroll
    for (int m = 0; m < MR; ++m)
#pragma unroll
      for (int n = 0; n < NR; ++n)
        acc[m][n] = __builtin_amdgcn_mfma_f32_16x16x32_bf16(af[m], bf[n], acc[m][n], 0, 0, 0);
    __builtin_amdgcn_s_setprio(0);
  };

  short8 afA[MR], bfA[NR], afB[MR], bfB[NR];

  const int nk = K >> 5;               // 40 (even)
  stage(0, 0);
  stage(1, 1);
  asm volatile("s_waitcnt vmcnt(4)" ::: "memory");
  __builtin_amdgcn_s_barrier();
  read_frags(0, afA, bfA);

  for (int t = 0; t < nk; t += 2){
    // ---- even sub-iter: MFMA(t) on bank A, read frags(t+1) into bank B
    if (t + 2 < nk){
      stage((t + 2) & 3, t + 2);
      asm volatile("s_waitcnt vmcnt(4)" ::: "memory");   // slot t+1 landed
    } else {
      asm volatile("s_waitcnt vmcnt(0)" ::: "memory");
    }
    __builtin_amdgcn_s_barrier();
    read_frags(t + 1, afB, bfB);
    do_mfma(afA, bfA);

    // ---- odd sub-iter: MFMA(t+1) on bank B, read frags(t+2) into bank A
    if (t + 3 < nk){
      stage((t + 3) & 3, t + 3);
      asm volatile("s_waitcnt vmcnt(4)" ::: "memory");   // slot t+2 landed
    } else {
      asm volatile("s_waitcnt vmcnt(0)" ::: "memory");
    }
    __builtin_amdgcn_s_barrier();
    if (t + 2 < nk) read_frags(t + 2, afA, bfA);
    do_mfma(afB, bfB);
  }
  __syncthreads();   // drain all LDS reads before epilogue reuses SH

  if (MODE == 0){
    // coalesced scatter epilogue: two 128-row phases staged in LDS
    unsigned short* Cs = SH;
    const int CSTR = 264;                  // 128 x 264 = 33792 shorts
    const int mat = col0 / E_DIM;          // tile-uniform (1280 % 256 == 0)
    const int cc0 = col0 - mat * E_DIM;
    unsigned short* dst = (mat == 0) ? Oq : ((mat == 1) ? Ok : Ov);
    float bb[NR];
#pragma unroll
    for (int n = 0; n < NR; ++n){
      int cc = cc0 + wn * 64 + n * 16 + (lane & 15);
      bb[n] = (mat == 0) ? bias0[cc] : (mat == 2 ? bias1[cc] : 0.0f);
    }
#pragma unroll
    for (int ph = 0; ph < 2; ++ph){
      if (wm == ph){
#pragma unroll
        for (int m = 0; m < MR; ++m)
#pragma unroll
          for (int n = 0; n < NR; ++n)
#pragma unroll
            for (int j = 0; j < 4; ++j){
              int rr = m * 16 + (lane >> 4) * 4 + j;      // 0..127
              int c  = wn * 64 + n * 16 + (lane & 15);    // 0..255
              Cs[rr * CSTR + c] = f2bf(acc[m][n][j] + bb[n]);
            }
      }
      __syncthreads();
#pragma unroll
      for (int i = 0; i < 8; ++i){
        int tk  = i * 512 + tid;        // 4096 tasks = 4 head-panels x 128r x 8sl
        int p   = tk >> 10;
        int idx = tk & 1023;
        int rr  = idx >> 3, sq = idx & 7;
        short8 vv = *reinterpret_cast<const short8*>(&Cs[rr * CSTR + p * 64 + sq * 8]);
        int gr = row0 + ph * 128 + rr;
        int hh = (cc0 >> 6) + p;
        *reinterpret_cast<short8*>(&dst[((size_t)hh * S_TOK + gr) * D_HEAD + sq * 8]) = vv;
      }
      __syncthreads();
    }
  } else {
#pragma unroll
    for (int m = 0; m < MR; ++m)
#pragma unroll
      for (int n = 0; n < NR; ++n){
        int c = col0 + wn * 64 + n * 16 + (lane & 15);
        float b = bias0[c];
#pragma unroll
        for (int j = 0; j < 4; ++j){
          int r = row0 + wm * 64 + m * 16 + (lane >> 4) * 4 + j;
          Of[(size_t)r * E_DIM + c] = acc[m][n][j] + b;
        }
      }
  }
}

// ---------------- block-diagonal attention ----------------
// grid = H*NSEG*3 blocks of 256 threads (4 waves x 16 Q-rows = 64 rows/block).
#define VSTR 200
#define PSTR 72
__global__ __launch_bounds__(256, 3) void attn_kernel(
    const unsigned short* __restrict__ Q,
    const unsigned short* __restrict__ Kb,
    const unsigned short* __restrict__ V,
    const int* __restrict__ cu,
    unsigned short* __restrict__ O)
{
  __shared__ __align__(16) unsigned short Vt[64*VSTR];     // [d][k-row]
  __shared__ __align__(16) unsigned short Pw[4][16][PSTR]; // per-wave scratch

  const int bid  = blockIdx.x;
  const int unit = bid / 3;
  const int third= bid - unit*3;
  const int h    = unit >> 4;
  const int seg  = unit & 15;
  const int s0   = cu[seg];
  const int L    = cu[seg + 1] - s0;
  if (L <= 0) return;

  const int tid  = threadIdx.x;
  const int lane = tid & 63;
  const int w    = tid >> 6;
  const int row0g = third*64 + w*16;

  const unsigned short* qh = Q  + (size_t)h * S_TOK * D_HEAD;
  const unsigned short* kh = Kb + (size_t)h * S_TOK * D_HEAD;
  const unsigned short* vh = V  + (size_t)h * S_TOK * D_HEAD;

#pragma unroll
  for (int i = 0; i < 6; ++i){
    int task = i*256 + tid;            // 1536 tasks = 192 rows x 8 d-groups
    int sr   = task % 192;
    int grp  = task / 192;
    int svr  = s0 + (sr < L ? sr : L - 1);
    short8 vv = *reinterpret_cast<const short8*>(vh + (size_t)svr*64 + grp*8);
#pragma unroll
    for (int j = 0; j < 8; ++j) Vt[(grp*8 + j)*VSTR + sr] = (unsigned short)vv[j];
  }

  short8 qf[2];
#pragma unroll
  for (int kk = 0; kk < 2; ++kk){
    int r  = row0g + (lane & 15);
    int sr = s0 + (r < L ? r : L - 1);
    qf[kk] = *reinterpret_cast<const short8*>(qh + (size_t)sr*64 + kk*32 + (lane >> 4)*8);
  }

  __syncthreads();

  const f32x4 fz = {0.f, 0.f, 0.f, 0.f};
  const float SCL = 0.125f * 1.44269504088896f;

  f32x4 sacc[12];
#pragma unroll
  for (int nt = 0; nt < 12; ++nt) sacc[nt] = fz;

#pragma unroll
  for (int nt = 0; nt < 12; ++nt){
    int rb = nt*16 + (lane & 15);
    int sr = s0 + (rb < L ? rb : L - 1);
    const unsigned short* kr = kh + (size_t)sr*64 + (lane >> 4)*8;
    short8 kf0 = *reinterpret_cast<const short8*>(kr);
    short8 kf1 = *reinterpret_cast<const short8*>(kr + 32);
    sacc[nt] = __builtin_amdgcn_mfma_f32_16x16x32_bf16(qf[0], kf0, sacc[nt], 0, 0, 0);
    sacc[nt] = __builtin_amdgcn_mfma_f32_16x16x32_bf16(qf[1], kf1, sacc[nt], 0, 0, 0);
  }

  float rinv[4];
#pragma unroll
  for (int j = 0; j < 4; ++j){
    float mx = -1e30f;
#pragma unroll
    for (int nt = 0; nt < 12; ++nt){
      int c = nt*16 + (lane & 15);
      float vv = (c < L) ? sacc[nt][j] : -1e30f;
      sacc[nt][j] = vv;
      mx = fmaxf(mx, vv);
    }
    mx = fmaxf(mx, __shfl_xor(mx, 1, 64));
    mx = fmaxf(mx, __shfl_xor(mx, 2, 64));
    mx = fmaxf(mx, __shfl_xor(mx, 4, 64));
    mx = fmaxf(mx, __shfl_xor(mx, 8, 64));
    float sum = 0.f;
#pragma unroll
    for (int nt = 0; nt < 12; ++nt){
      float pp = exp2f((sacc[nt][j] - mx) * SCL);
      sacc[nt][j] = pp;
      sum += pp;
    }
    sum += __shfl_xor(sum, 1, 64);
    sum += __shfl_xor(sum, 2, 64);
    sum += __shfl_xor(sum, 4, 64);
    sum += __shfl_xor(sum, 8, 64);
    rinv[j] = 1.0f / sum;
  }

  f32x4 oacc[4];
#pragma unroll
  for (int nt = 0; nt < 4; ++nt) oacc[nt] = fz;

#pragma unroll
  for (int kk = 0; kk < 6; ++kk){
#pragma unroll
    for (int ntl = 0; ntl < 2; ++ntl){
      int nt = kk*2 + ntl;
#pragma unroll
      for (int j = 0; j < 4; ++j)
        Pw[w][(lane >> 4)*4 + j][ntl*16 + (lane & 15)] = f2bf(sacc[nt][j]);
    }
    short8 pf = *reinterpret_cast<const short8*>(&Pw[w][lane & 15][(lane >> 4)*8]);
#pragma unroll
    for (int nt4 = 0; nt4 < 4; ++nt4){
      int dcol = nt4*16 + (lane & 15);
      short8 vf = *reinterpret_cast<const short8*>(&Vt[dcol*VSTR + kk*32 + (lane >> 4)*8]);
      oacc[nt4] = __builtin_amdgcn_mfma_f32_16x16x32_bf16(pf, vf, oacc[nt4], 0, 0, 0);
    }
  }

#pragma unroll
  for (int nt4 = 0; nt4 < 4; ++nt4)
#pragma unroll
    for (int j = 0; j < 4; ++j)
      Pw[w][(lane >> 4)*4 + j][nt4*16 + (lane & 15)] = f2bf(oacc[nt4][j] * rinv[j]);

  {
    int r = lane >> 2;
    int gr = row0g + r;
    if (gr < L){
#pragma unroll
      for (int part = 0; part < 2; ++part){
        int c0 = (lane & 3)*16 + part*8;
        short8 vv = *reinterpret_cast<const short8*>(&Pw[w][r][c0]);
        *reinterpret_cast<short8*>(&O[(size_t)(s0 + gr) * E_DIM + h*64 + c0]) = vv;
      }
    }
  }
}

// ---------------- host launch ----------------
extern "C" void kernel_launch(void* const* d_in, const int* in_sizes, int n_in,
                              void* d_out, int out_size, void* d_ws, size_t ws_size,
                              hipStream_t stream)
{
  const float* hs = (const float*)d_in[0];
  const float* Wq = (const float*)d_in[1];
  const float* bq = (const float*)d_in[2];
  const float* Wk = (const float*)d_in[3];
  const float* Wv = (const float*)d_in[4];
  const float* bv = (const float*)d_in[5];
  const float* Wo = (const float*)d_in[6];
  const float* bo = (const float*)d_in[7];
  const int*   cu = (const int*)d_in[8];
  float* out = (float*)d_out;

  unsigned short* p = (unsigned short*)d_ws;
  unsigned short* hsb  = p; p += (size_t)S_TOK * E_DIM;
  unsigned short* wqkv = p; p += (size_t)3 * E_DIM * E_DIM;
  unsigned short* wob  = p; p += (size_t)E_DIM * E_DIM;
  unsigned short* qb   = p; p += (size_t)S_TOK * E_DIM;
  unsigned short* kb   = p; p += (size_t)S_TOK * E_DIM;
  unsigned short* vb   = p; p += (size_t)S_TOK * E_DIM;
  unsigned short* aob  = p; p += (size_t)S_TOK * E_DIM;

  const int nHS4 = S_TOK * E_DIM / 4;
  const int nW4  = E_DIM * E_DIM / 4;
  const int nCvt = nHS4 + 4 * nW4;
  cvt_all<<<(nCvt + 255) / 256, 256, 0, stream>>>(hs, Wq, Wk, Wv, Wo, hsb, wqkv, wob, nHS4, nW4);

  // QKV: 12 x 15 = 180 blocks of 512
  gemm_pipe<0, 512><<<(S_TOK/256) * (3*E_DIM/256), 512, 0, stream>>>(
      hsb, wqkv, bq, bv, qb, kb, vb, nullptr, S_TOK, 3*E_DIM, E_DIM);

  attn_kernel<<<H_NUM * NSEG * 3, 256, 0, stream>>>(qb, kb, vb, cu, aob);

  // out-proj: 24 x 10 = 240 blocks of 256
  gemm_pipe<1, 256><<<(S_TOK/128) * (E_DIM/128), 256, 0, stream>>>(
      aob, wob, bo, nullptr, nullptr, nullptr, nullptr, out, S_TOK, E_DIM, E_DIM);
}

// Round 11
// 97.751 us; speedup vs baseline: 1.4403x; 1.0456x over previous
//
#include <hip/hip_runtime.h>
#include <hip/hip_bf16.h>
#include <stdint.h>

#define S_TOK 3072
#define E_DIM 1280
#define H_NUM 20
#define D_HEAD 64
#define NSEG 16

typedef __attribute__((ext_vector_type(8))) short short8;
typedef __attribute__((ext_vector_type(4))) float f32x4;

__device__ __forceinline__ unsigned short f2bf(float f){
  union { float f; unsigned int i; } u; u.f = f;
  unsigned int r = u.i + 0x7FFFu + ((u.i >> 16) & 1u);
  return (unsigned short)(r >> 16);
}

__device__ __forceinline__ void gload_lds16(const void* g, void* l){
  __builtin_amdgcn_global_load_lds((__attribute__((address_space(1))) void*)(g),
                                   (__attribute__((address_space(3))) void*)(l), 16, 0, 0);
}

// -------- f32 -> bf16 conversions for hs + Wq/Wk/Wv (Wo is fused into attn) --------
__global__ void cvt_all(const float* __restrict__ hs,
                        const float* __restrict__ w0, const float* __restrict__ w1,
                        const float* __restrict__ w2,
                        unsigned short* __restrict__ hsb,
                        unsigned short* __restrict__ dqkv,
                        int nHS4, int nW4){
  int i = blockIdx.x * blockDim.x + threadIdx.x;
  const float* src;
  unsigned short* dst;
  size_t sj, dj;
  if (i < nHS4){
    src = hs; dst = hsb; sj = i; dj = i;
  } else {
    int t = i - nHS4;
    int w = t / nW4;
    if (w >= 3) return;
    int j = t - w * nW4;
    src = (w == 0) ? w0 : (w == 1) ? w1 : w2;
    sj = j;
    dst = dqkv; dj = (size_t)w * nW4 + j;
  }
  float4 v = reinterpret_cast<const float4*>(src)[sj];
  ushort4 o;
  o.x = f2bf(v.x); o.y = f2bf(v.y); o.z = f2bf(v.z); o.w = f2bf(v.w);
  reinterpret_cast<ushort4*>(dst)[dj] = o;
}

// ---------------- GEMM: C = A[M,K] @ B[N,K]^T (bf16 in, f32 acc) ----------------
// BK=64 (20 iters), ring-2 double buffer, ONE barrier + ONE vmcnt(0) per iter:
//   top of t: vmcnt(0)  [t's 8 loads done; issued 1 full iter (~2800cyc) ago]
//             barrier   [all waves done reading buf^1 -> overwrite safe]
//             stage(t+1) into buf^1; ds_read frags(t) from buf; 64 MFMA.
// Rationale: per-iter stall tax (~1400cyc) is schedule-invariant (r6/r7/r8/r10
// all 2770cyc/iter at BK=32); halving iteration count halves the tax.
// Swizzle: phys 16B-slot p of row r holds k-chunk p^(r&7) (r7: ~0 conflicts).
// MODE 0: BM=BN=256, 8 waves (2x4), wave-tile 128x64, scatter q/k/v bf16.
// MODE 1: BM=BN=128, 4 waves (2x2), wave-tile 64x64, f32 out + bias, 2 blk/CU.
template<int MODE, int BLOCK>
__global__ __launch_bounds__(BLOCK, 2) void gemm_k64(
    const unsigned short* __restrict__ A,
    const unsigned short* __restrict__ Bp,
    const float* __restrict__ bias0,
    const float* __restrict__ bias1,
    unsigned short* __restrict__ Oq,
    unsigned short* __restrict__ Ok,
    unsigned short* __restrict__ Ov,
    float* __restrict__ Of,
    int M, int N, int K)
{
  constexpr int BM = (MODE == 0) ? 256 : 128;
  constexpr int BN = BM;
  constexpr int WN = (MODE == 0) ? 4 : 2;
  constexpr int WM = (BLOCK / 64) / WN;
  constexpr int MR = BM / WM / 16;        // 8 / 4
  constexpr int NR = BN / WN / 16;        // 4 / 4
  constexpr int SLOT = (BM + BN) * 64;    // shorts per ring slot (A then B)

  __shared__ __align__(16) unsigned short SH[2 * SLOT];

  const int nbn = N >> (MODE == 0 ? 8 : 7);
  // supertile remap (4bm x 5bn chunks) for L2 locality (nbm%4==0, nbn%5==0)
  const int sgn = nbn / 5;
  const int st = blockIdx.x / 20, ii = blockIdx.x % 20;
  const int bm = (st / sgn) * 4 + ii / 5;
  const int bn = (st % sgn) * 5 + ii % 5;
  const int row0 = bm * BM;
  const int col0 = bn * BN;

  const int tid  = threadIdx.x;
  const int lane = tid & 63;
  const int w    = tid >> 6;
  const int wm   = (MODE == 0) ? (w >> 2) : (w >> 1);
  const int wn   = (MODE == 0) ? (w & 3) : (w & 1);

  const f32x4 fz = {0.f, 0.f, 0.f, 0.f};
  f32x4 acc[MR][NR];
#pragma unroll
  for (int m = 0; m < MR; ++m)
#pragma unroll
    for (int n = 0; n < NR; ++n) acc[m][n] = fz;

  // staging: (BM+BN)*8 16B-slots, 8 per thread
  auto stage = [&](int buf, int t){
    unsigned short* base = SH + buf * SLOT;
    const int k0 = t << 6;
#pragma unroll
    for (int i = 0; i < 8; ++i){
      int s = i * BLOCK + tid;
      int r = s >> 3, p = s & 7;
      int ks = p ^ (r & 7);
      const unsigned short* g = (r < BM)
          ? A  + (size_t)(row0 + r) * K + k0 + ks * 8
          : Bp + (size_t)(col0 + (r - BM)) * K + k0 + ks * 8;
      gload_lds16(g, base + s * 8);
    }
  };

  const int nk = K >> 6;                 // 20
  stage(0, 0);
  int buf = 0;
  for (int t = 0; t < nk; ++t){
    asm volatile("s_waitcnt vmcnt(0)" ::: "memory");
    __builtin_amdgcn_s_barrier();
    if (t + 1 < nk) stage(buf ^ 1, t + 1);

    const unsigned short* As = SH + buf * SLOT;
    const unsigned short* Bs = As + BM * 64;
    short8 af[MR][2], bf[NR][2];
#pragma unroll
    for (int n = 0; n < NR; ++n){
      int rb = wn * (BN / WN) + n * 16 + (lane & 15);
#pragma unroll
      for (int kk = 0; kk < 2; ++kk){
        int slot = kk * 4 + (lane >> 4);
        bf[n][kk] = *reinterpret_cast<const short8*>(&Bs[rb * 64 + ((slot ^ (rb & 7))) * 8]);
      }
    }
#pragma unroll
    for (int m = 0; m < MR; ++m){
      int ra = wm * (BM / WM) + m * 16 + (lane & 15);
#pragma unroll
      for (int kk = 0; kk < 2; ++kk){
        int slot = kk * 4 + (lane >> 4);
        af[m][kk] = *reinterpret_cast<const short8*>(&As[ra * 64 + ((slot ^ (ra & 7))) * 8]);
      }
    }
    __builtin_amdgcn_s_setprio(1);
#pragma unroll
    for (int kk = 0; kk < 2; ++kk)
#pragma unroll
      for (int m = 0; m < MR; ++m)
#pragma unroll
        for (int n = 0; n < NR; ++n)
          acc[m][n] = __builtin_amdgcn_mfma_f32_16x16x32_bf16(af[m][kk], bf[n][kk], acc[m][n], 0, 0, 0);
    __builtin_amdgcn_s_setprio(0);
    buf ^= 1;
  }
  __syncthreads();   // drain all LDS reads before epilogue reuses SH

  if (MODE == 0){
    // coalesced scatter epilogue: two 128-row phases staged in LDS
    unsigned short* Cs = SH;
    const int CSTR = 264;                  // 128 x 264 = 33792 shorts <= 2*SLOT
    const int mat = col0 / E_DIM;          // tile-uniform (1280 % 256 == 0)
    const int cc0 = col0 - mat * E_DIM;
    unsigned short* dst = (mat == 0) ? Oq : ((mat == 1) ? Ok : Ov);
    float bb[NR];
#pragma unroll
    for (int n = 0; n < NR; ++n){
      int cc = cc0 + wn * 64 + n * 16 + (lane & 15);
      bb[n] = (mat == 0) ? bias0[cc] : (mat == 2 ? bias1[cc] : 0.0f);
    }
#pragma unroll
    for (int ph = 0; ph < 2; ++ph){
      if (wm == ph){
#pragma unroll
        for (int m = 0; m < MR; ++m)
#pragma unroll
          for (int n = 0; n < NR; ++n)
#pragma unroll
            for (int j = 0; j < 4; ++j){
              int rr = m * 16 + (lane >> 4) * 4 + j;      // 0..127
              int c  = wn * 64 + n * 16 + (lane & 15);    // 0..255
              Cs[rr * CSTR + c] = f2bf(acc[m][n][j] + bb[n]);
            }
      }
      __syncthreads();
#pragma unroll
      for (int i = 0; i < 8; ++i){
        int tk  = i * 512 + tid;        // 4096 tasks = 4 head-panels x 128r x 8sl
        int p   = tk >> 10;
        int idx = tk & 1023;
        int rr  = idx >> 3, sq = idx & 7;
        short8 vv = *reinterpret_cast<const short8*>(&Cs[rr * CSTR + p * 64 + sq * 8]);
        int gr = row0 + ph * 128 + rr;
        int hh = (cc0 >> 6) + p;
        *reinterpret_cast<short8*>(&dst[((size_t)hh * S_TOK + gr) * D_HEAD + sq * 8]) = vv;
      }
      __syncthreads();
    }
  } else {
#pragma unroll
    for (int m = 0; m < MR; ++m)
#pragma unroll
      for (int n = 0; n < NR; ++n){
        int c = col0 + wn * 64 + n * 16 + (lane & 15);
        float b = bias0[c];
#pragma unroll
        for (int j = 0; j < 4; ++j){
          int r = row0 + wm * 64 + m * 16 + (lane >> 4) * 4 + j;
          Of[(size_t)r * E_DIM + c] = acc[m][n][j] + b;
        }
      }
  }
}

// ---------------- block-diagonal attention (+fused Wo f32->bf16 cvt) ----------------
// blocks 0..959: attention (4 waves x 16 Q-rows = 64 rows). blocks >=960: Wo cvt.
#define VSTR 200
#define PSTR 72
#define ATTN_BLKS (H_NUM * NSEG * 3)
__global__ __launch_bounds__(256, 3) void attn_kernel(
    const unsigned short* __restrict__ Q,
    const unsigned short* __restrict__ Kb,
    const unsigned short* __restrict__ V,
    const int* __restrict__ cu,
    unsigned short* __restrict__ O,
    const float* __restrict__ Wo,
    unsigned short* __restrict__ wob,
    int nW4)
{
  __shared__ __align__(16) unsigned short Vt[64*VSTR];     // [d][k-row]
  __shared__ __align__(16) unsigned short Pw[4][16][PSTR]; // per-wave scratch

  const int bid  = blockIdx.x;
  if (bid >= ATTN_BLKS){
    int i = (bid - ATTN_BLKS) * 256 + threadIdx.x;
    if (i < nW4){
      float4 v = reinterpret_cast<const float4*>(Wo)[i];
      ushort4 o;
      o.x = f2bf(v.x); o.y = f2bf(v.y); o.z = f2bf(v.z); o.w = f2bf(v.w);
      reinterpret_cast<ushort4*>(wob)[i] = o;
    }
    return;
  }
  const int unit = bid / 3;
  const int third= bid - unit*3;
  const int h    = unit >> 4;
  const int seg  = unit & 15;
  const int s0   = cu[seg];
  const int L    = cu[seg + 1] - s0;
  if (L <= 0) return;

  const int tid  = threadIdx.x;
  const int lane = tid & 63;
  const int w    = tid >> 6;
  const int row0g = third*64 + w*16;

  const unsigned short* qh = Q  + (size_t)h * S_TOK * D_HEAD;
  const unsigned short* kh = Kb + (size_t)h * S_TOK * D_HEAD;
  const unsigned short* vh = V  + (size_t)h * S_TOK * D_HEAD;

#pragma unroll
  for (int i = 0; i < 6; ++i){
    int task = i*256 + tid;            // 1536 tasks = 192 rows x 8 d-groups
    int sr   = task % 192;
    int grp  = task / 192;
    int svr  = s0 + (sr < L ? sr : L - 1);
    short8 vv = *reinterpret_cast<const short8*>(vh + (size_t)svr*64 + grp*8);
#pragma unroll
    for (int j = 0; j < 8; ++j) Vt[(grp*8 + j)*VSTR + sr] = (unsigned short)vv[j];
  }

  short8 qf[2];
#pragma unroll
  for (int kk = 0; kk < 2; ++kk){
    int r  = row0g + (lane & 15);
    int sr = s0 + (r < L ? r : L - 1);
    qf[kk] = *reinterpret_cast<const short8*>(qh + (size_t)sr*64 + kk*32 + (lane >> 4)*8);
  }

  __syncthreads();

  const f32x4 fz = {0.f, 0.f, 0.f, 0.f};
  const float SCL = 0.125f * 1.44269504088896f;

  f32x4 sacc[12];
#pragma unroll
  for (int nt = 0; nt < 12; ++nt) sacc[nt] = fz;

#pragma unroll
  for (int nt = 0; nt < 12; ++nt){
    int rb = nt*16 + (lane & 15);
    int sr = s0 + (rb < L ? rb : L - 1);
    const unsigned short* kr = kh + (size_t)sr*64 + (lane >> 4)*8;
    short8 kf0 = *reinterpret_cast<const short8*>(kr);
    short8 kf1 = *reinterpret_cast<const short8*>(kr + 32);
    sacc[nt] = __builtin_amdgcn_mfma_f32_16x16x32_bf16(qf[0], kf0, sacc[nt], 0, 0, 0);
    sacc[nt] = __builtin_amdgcn_mfma_f32_16x16x32_bf16(qf[1], kf1, sacc[nt], 0, 0, 0);
  }

  float rinv[4];
#pragma unroll
  for (int j = 0; j < 4; ++j){
    float mx = -1e30f;
#pragma unroll
    for (int nt = 0; nt < 12; ++nt){
      int c = nt*16 + (lane & 15);
      float vv = (c < L) ? sacc[nt][j] : -1e30f;
      sacc[nt][j] = vv;
      mx = fmaxf(mx, vv);
    }
    mx = fmaxf(mx, __shfl_xor(mx, 1, 64));
    mx = fmaxf(mx, __shfl_xor(mx, 2, 64));
    mx = fmaxf(mx, __shfl_xor(mx, 4, 64));
    mx = fmaxf(mx, __shfl_xor(mx, 8, 64));
    float sum = 0.f;
#pragma unroll
    for (int nt = 0; nt < 12; ++nt){
      float pp = exp2f((sacc[nt][j] - mx) * SCL);
      sacc[nt][j] = pp;
      sum += pp;
    }
    sum += __shfl_xor(sum, 1, 64);
    sum += __shfl_xor(sum, 2, 64);
    sum += __shfl_xor(sum, 4, 64);
    sum += __shfl_xor(sum, 8, 64);
    rinv[j] = 1.0f / sum;
  }

  f32x4 oacc[4];
#pragma unroll
  for (int nt = 0; nt < 4; ++nt) oacc[nt] = fz;

#pragma unroll
  for (int kk = 0; kk < 6; ++kk){
#pragma unroll
    for (int ntl = 0; ntl < 2; ++ntl){
      int nt = kk*2 + ntl;
#pragma unroll
      for (int j = 0; j < 4; ++j)
        Pw[w][(lane >> 4)*4 + j][ntl*16 + (lane & 15)] = f2bf(sacc[nt][j]);
    }
    short8 pf = *reinterpret_cast<const short8*>(&Pw[w][lane & 15][(lane >> 4)*8]);
#pragma unroll
    for (int nt4 = 0; nt4 < 4; ++nt4){
      int dcol = nt4*16 + (lane & 15);
      short8 vf = *reinterpret_cast<const short8*>(&Vt[dcol*VSTR + kk*32 + (lane >> 4)*8]);
      oacc[nt4] = __builtin_amdgcn_mfma_f32_16x16x32_bf16(pf, vf, oacc[nt4], 0, 0, 0);
    }
  }

#pragma unroll
  for (int nt4 = 0; nt4 < 4; ++nt4)
#pragma unroll
    for (int j = 0; j < 4; ++j)
      Pw[w][(lane >> 4)*4 + j][nt4*16 + (lane & 15)] = f2bf(oacc[nt4][j] * rinv[j]);

  {
    int r = lane >> 2;
    int gr = row0g + r;
    if (gr < L){
#pragma unroll
      for (int part = 0; part < 2; ++part){
        int c0 = (lane & 3)*16 + part*8;
        short8 vv = *reinterpret_cast<const short8*>(&Pw[w][r][c0]);
        *reinterpret_cast<short8*>(&O[(size_t)(s0 + gr) * E_DIM + h*64 + c0]) = vv;
      }
    }
  }
}

// ---------------- host launch ----------------
extern "C" void kernel_launch(void* const* d_in, const int* in_sizes, int n_in,
                              void* d_out, int out_size, void* d_ws, size_t ws_size,
                              hipStream_t stream)
{
  const float* hs = (const float*)d_in[0];
  const float* Wq = (const float*)d_in[1];
  const float* bq = (const float*)d_in[2];
  const float* Wk = (const float*)d_in[3];
  const float* Wv = (const float*)d_in[4];
  const float* bv = (const float*)d_in[5];
  const float* Wo = (const float*)d_in[6];
  const float* bo = (const float*)d_in[7];
  const int*   cu = (const int*)d_in[8];
  float* out = (float*)d_out;

  unsigned short* p = (unsigned short*)d_ws;
  unsigned short* hsb  = p; p += (size_t)S_TOK * E_DIM;
  unsigned short* wqkv = p; p += (size_t)3 * E_DIM * E_DIM;
  unsigned short* wob  = p; p += (size_t)E_DIM * E_DIM;
  unsigned short* qb   = p; p += (size_t)S_TOK * E_DIM;
  unsigned short* kb   = p; p += (size_t)S_TOK * E_DIM;
  unsigned short* vb   = p; p += (size_t)S_TOK * E_DIM;
  unsigned short* aob  = p; p += (size_t)S_TOK * E_DIM;

  const int nHS4 = S_TOK * E_DIM / 4;
  const int nW4  = E_DIM * E_DIM / 4;
  const int nCvt = nHS4 + 3 * nW4;
  cvt_all<<<(nCvt + 255) / 256, 256, 0, stream>>>(hs, Wq, Wk, Wv, hsb, wqkv, nHS4, nW4);

  // QKV: 12 x 15 = 180 blocks of 512, BK=64
  gemm_k64<0, 512><<<(S_TOK/256) * (3*E_DIM/256), 512, 0, stream>>>(
      hsb, wqkv, bq, bv, qb, kb, vb, nullptr, S_TOK, 3*E_DIM, E_DIM);

  // attention (960 blocks) + fused Wo conversion (1600 blocks)
  const int cvtWoBlks = (nW4 + 255) / 256;
  attn_kernel<<<ATTN_BLKS + cvtWoBlks, 256, 0, stream>>>(
      qb, kb, vb, cu, aob, Wo, wob, nW4);

  // out-proj: 24 x 10 = 240 blocks of 256, BK=64, 2 blocks/CU
  gemm_k64<1, 256><<<(S_TOK/128) * (E_DIM/128), 256, 0, stream>>>(
      aob, wob, bo, nullptr, nullptr, nullptr, nullptr, out, S_TOK, E_DIM, E_DIM);
}

// Round 12
// 93.760 us; speedup vs baseline: 1.5016x; 1.0426x over previous
//
#include <hip/hip_runtime.h>
#include <hip/hip_bf16.h>
#include <stdint.h>

#define S_TOK 3072
#define E_DIM 1280
#define H_NUM 20
#define D_HEAD 64
#define NSEG 16

typedef __attribute__((ext_vector_type(8))) short short8;
typedef __attribute__((ext_vector_type(4))) float f32x4;

__device__ __forceinline__ unsigned short f2bf(float f){
  union { float f; unsigned int i; } u; u.f = f;
  unsigned int r = u.i + 0x7FFFu + ((u.i >> 16) & 1u);
  return (unsigned short)(r >> 16);
}

__device__ __forceinline__ void gload_lds16(const void* g, void* l){
  __builtin_amdgcn_global_load_lds((__attribute__((address_space(1))) void*)(g),
                                   (__attribute__((address_space(3))) void*)(l), 16, 0, 0);
}

// -------- f32 -> bf16 conversions for hs + Wq/Wk/Wv (Wo fused into attn) --------
__global__ void cvt_all(const float* __restrict__ hs,
                        const float* __restrict__ w0, const float* __restrict__ w1,
                        const float* __restrict__ w2,
                        unsigned short* __restrict__ hsb,
                        unsigned short* __restrict__ dqkv,
                        int nHS4, int nW4){
  int i = blockIdx.x * blockDim.x + threadIdx.x;
  const float* src;
  unsigned short* dst;
  size_t sj, dj;
  if (i < nHS4){
    src = hs; dst = hsb; sj = i; dj = i;
  } else {
    int t = i - nHS4;
    int w = t / nW4;
    if (w >= 3) return;
    int j = t - w * nW4;
    src = (w == 0) ? w0 : (w == 1) ? w1 : w2;
    sj = j;
    dst = dqkv; dj = (size_t)w * nW4 + j;
  }
  float4 v = reinterpret_cast<const float4*>(src)[sj];
  ushort4 o;
  o.x = f2bf(v.x); o.y = f2bf(v.y); o.z = f2bf(v.z); o.w = f2bf(v.w);
  reinterpret_cast<ushort4*>(dst)[dj] = o;
}

// ---------------- 4-phase counted-vmcnt GEMM: C = A[M,K] @ B[N,K]^T ----------------
// BK=64 per tile, stored as 4 half-tiles {A0,A1,B0,B1} of HR rows x 64, double
// buffered (dbuf = t&1). Per tile 4 phases = 4 C-quadrants in order
// (mh,nh) = (0,0),(0,1),(1,1),(1,0); stage order of tile t+1: A0,B0,B1,A1 at
// phases q0..q3. Per-thread vmcnt ledger (2 loads per half-tile stage):
//   start q0: 8 out -> vmcnt(4) forces A0,B0(t)   [q0 reads them]
//   start q1: 6 out -> vmcnt(4) forces B1(t)      [q1 reads it]
//   start q2: 6 out -> vmcnt(4) forces A1(t)      [q2 reads it]
//   q3: register-only (af reread at q2; bf0 held from q0) - no wait.
// Last tile (no stages): q1 -> vmcnt(2), q2 -> vmcnt(0). Nothing over-drained.
// MODE 0: BM=BN=256, 8 waves (2x4), scatter q/k/v bf16 [H][S][D].
// MODE 1: BM=BN=128, 4 waves (2x2), f32 out + bias.
template<int MODE>
__global__ __launch_bounds__(MODE==0?512:256, 2) void gemm_ph(
    const unsigned short* __restrict__ A,
    const unsigned short* __restrict__ Bp,
    const float* __restrict__ bias0,
    const float* __restrict__ bias1,
    unsigned short* __restrict__ Oq,
    unsigned short* __restrict__ Ok,
    unsigned short* __restrict__ Ov,
    float* __restrict__ Of,
    int M, int N, int K)
{
  constexpr int BM    = MODE==0 ? 256 : 128;
  constexpr int BLOCK = MODE==0 ? 512 : 256;
  constexpr int HR    = BM/2;
  constexpr int HS    = HR*64;            // shorts per half-tile
  constexpr int MR2   = MODE==0 ? 4 : 2;  // m-frags per quadrant

  __shared__ __align__(16) unsigned short SH[8*HS];  // 2 dbuf x {A0,A1,B0,B1}

  // XCD-aware bijective remap (m204), then 4x5 supertile decomposition
  const int nwg = gridDim.x;
  const int xcd = blockIdx.x & 7, ix = blockIdx.x >> 3;
  const int qq = nwg >> 3, rr8 = nwg & 7;
  const int wg = (xcd < rr8 ? xcd*(qq+1) : rr8*(qq+1) + (xcd-rr8)*qq) + ix;
  const int nbn = N / BM;
  const int sgn = nbn / 5;
  const int st = wg / 20, ii = wg % 20;
  const int bm = (st / sgn) * 4 + ii / 5;
  const int bn = (st % sgn) * 5 + ii % 5;
  const int row0 = bm * BM, col0 = bn * BM;

  const int tid  = threadIdx.x;
  const int lane = tid & 63;
  const int w    = tid >> 6;
  const int wm   = MODE==0 ? (w >> 2) : (w >> 1);
  const int wn   = MODE==0 ? (w & 3) : (w & 1);

  const f32x4 fz = {0.f, 0.f, 0.f, 0.f};
  f32x4 acc[4][MR2][2];
#pragma unroll
  for (int qd = 0; qd < 4; ++qd)
#pragma unroll
    for (int m = 0; m < MR2; ++m)
#pragma unroll
      for (int n = 0; n < 2; ++n) acc[qd][m][n] = fz;

  // per-thread staging constants: half-tile = HR*8 slots = 2*BLOCK -> 2/thread
  const int s1 = tid, s2 = BLOCK + tid;
  const int r1 = s1 >> 3, ks1 = (s1 & 7) ^ (r1 & 7);
  const int r2 = s2 >> 3, ks2 = (s2 & 7) ^ (r2 & 7);

  auto stA = [&](int h, int t){
    unsigned short* d = SH + ((t & 1) * 4 + h) * HS;
    const unsigned short* g = A + (size_t)(row0 + h*HR) * K + (t << 6);
    gload_lds16(g + (size_t)r1*K + ks1*8, d + s1*8);
    gload_lds16(g + (size_t)r2*K + ks2*8, d + s2*8);
  };
  auto stB = [&](int h, int t){
    unsigned short* d = SH + ((t & 1) * 4 + 2 + h) * HS;
    const unsigned short* g = Bp + (size_t)(col0 + h*HR) * K + (t << 6);
    gload_lds16(g + (size_t)r1*K + ks1*8, d + s1*8);
    gload_lds16(g + (size_t)r2*K + ks2*8, d + s2*8);
  };

  short8 af[MR2][2], bf0[2][2], bf1[2][2];
  auto RA = [&](int mh, int db){
    const unsigned short* Ah = SH + (db*4 + mh)*HS;
#pragma unroll
    for (int m = 0; m < MR2; ++m){
      int ra = wm*(HR/2) + m*16 + (lane & 15);
#pragma unroll
      for (int kk = 0; kk < 2; ++kk){
        int sl = kk*4 + (lane >> 4);
        af[m][kk] = *reinterpret_cast<const short8*>(&Ah[ra*64 + ((sl ^ (ra & 7)))*8]);
      }
    }
  };
  auto RB = [&](int nh, int db, short8 (*bf)[2]){
    const unsigned short* Bh = SH + (db*4 + 2 + nh)*HS;
#pragma unroll
    for (int n = 0; n < 2; ++n){
      int rb = wn*32 + n*16 + (lane & 15);
#pragma unroll
      for (int kk = 0; kk < 2; ++kk){
        int sl = kk*4 + (lane >> 4);
        bf[n][kk] = *reinterpret_cast<const short8*>(&Bh[rb*64 + ((sl ^ (rb & 7)))*8]);
      }
    }
  };

#define MF_Q(QD, BF)                                                          \
  do {                                                                        \
    __builtin_amdgcn_s_setprio(1);                                            \
    _Pragma("unroll")                                                         \
    for (int kk = 0; kk < 2; ++kk)                                            \
      _Pragma("unroll")                                                       \
      for (int m = 0; m < MR2; ++m)                                           \
        _Pragma("unroll")                                                     \
        for (int n = 0; n < 2; ++n)                                           \
          acc[QD][m][n] = __builtin_amdgcn_mfma_f32_16x16x32_bf16(            \
              af[m][kk], BF[n][kk], acc[QD][m][n], 0, 0, 0);                  \
    __builtin_amdgcn_s_setprio(0);                                            \
  } while (0)

  const int nk = K >> 6;                 // 20
  // prologue: tile 0's halves in ledger order A0,B0,B1,A1 (8 loads out)
  stA(0,0); stB(0,0); stB(1,0); stA(1,0);

  for (int t = 0; t < nk; ++t){
    const int db = t & 1;
    const bool nx = (t + 1 < nk);
    // ---- q0: quadrant (0,0)
    asm volatile("s_waitcnt vmcnt(4)" ::: "memory");
    __builtin_amdgcn_s_barrier();
    RA(0, db); RB(0, db, bf0);
    if (nx) stA(0, t+1);
    asm volatile("s_waitcnt lgkmcnt(0)" ::: "memory");
    __builtin_amdgcn_sched_barrier(0);
    MF_Q(0, bf0);
    // ---- q1: quadrant (0,1)
    if (nx) asm volatile("s_waitcnt vmcnt(4)" ::: "memory");
    else    asm volatile("s_waitcnt vmcnt(2)" ::: "memory");
    __builtin_amdgcn_s_barrier();
    RB(1, db, bf1);
    if (nx) stB(0, t+1);
    asm volatile("s_waitcnt lgkmcnt(0)" ::: "memory");
    __builtin_amdgcn_sched_barrier(0);
    MF_Q(1, bf1);
    // ---- q2: quadrant (1,1)
    if (nx) asm volatile("s_waitcnt vmcnt(4)" ::: "memory");
    else    asm volatile("s_waitcnt vmcnt(0)" ::: "memory");
    __builtin_amdgcn_s_barrier();
    RA(1, db);
    if (nx) stB(1, t+1);
    asm volatile("s_waitcnt lgkmcnt(0)" ::: "memory");
    __builtin_amdgcn_sched_barrier(0);
    MF_Q(2, bf1);
    // ---- q3: quadrant (1,0) - register-only
    __builtin_amdgcn_s_barrier();
    if (nx) stA(1, t+1);
    MF_Q(3, bf0);
  }
  __syncthreads();   // all LDS reads complete before epilogue reuses SH

  if (MODE == 0){
    // coalesced scatter epilogue: two 128-row phases staged in LDS
    unsigned short* Cs = SH;
    const int CSTR = 264;                  // 128 x 264 = 33792 shorts <= 65536
    const int mat = col0 / E_DIM;          // tile-uniform (1280 % 256 == 0)
    const int cc0 = col0 - mat * E_DIM;
    unsigned short* dst = (mat == 0) ? Oq : ((mat == 1) ? Ok : Ov);
    float bb[2][2];
#pragma unroll
    for (int nh = 0; nh < 2; ++nh)
#pragma unroll
      for (int n = 0; n < 2; ++n){
        int cc = cc0 + nh*128 + wn*32 + n*16 + (lane & 15);
        bb[nh][n] = (mat == 0) ? bias0[cc] : (mat == 2 ? bias1[cc] : 0.0f);
      }
#pragma unroll
    for (int ph = 0; ph < 2; ++ph){
#pragma unroll
      for (int q2i = 0; q2i < 2; ++q2i){
        const int qd = ph*2 + q2i;
        const int nh = (qd >> 1) ^ (qd & 1);
#pragma unroll
        for (int m = 0; m < MR2; ++m)
#pragma unroll
          for (int n = 0; n < 2; ++n)
#pragma unroll
            for (int j = 0; j < 4; ++j){
              int rr = wm*64 + m*16 + (lane >> 4)*4 + j;        // 0..127
              int c  = nh*128 + wn*32 + n*16 + (lane & 15);     // 0..255
              Cs[rr * CSTR + c] = f2bf(acc[qd][m][n][j] + bb[nh][n]);
            }
      }
      __syncthreads();
#pragma unroll
      for (int i = 0; i < 8; ++i){
        int tk  = i * 512 + tid;        // 4096 tasks = 4 head-panels x 128r x 8sl
        int p   = tk >> 10;
        int idx = tk & 1023;
        int rr  = idx >> 3, sq = idx & 7;
        short8 vv = *reinterpret_cast<const short8*>(&Cs[rr * CSTR + p * 64 + sq * 8]);
        int gr = row0 + ph * 128 + rr;
        int hh = (cc0 >> 6) + p;
        *reinterpret_cast<short8*>(&dst[((size_t)hh * S_TOK + gr) * D_HEAD + sq * 8]) = vv;
      }
      __syncthreads();
    }
  } else {
    float bc[2][2];
#pragma unroll
    for (int nh = 0; nh < 2; ++nh)
#pragma unroll
      for (int n = 0; n < 2; ++n)
        bc[nh][n] = bias0[col0 + nh*64 + wn*32 + n*16 + (lane & 15)];
#pragma unroll
    for (int qd = 0; qd < 4; ++qd){
      const int mh = qd >> 1;
      const int nh = (qd >> 1) ^ (qd & 1);
#pragma unroll
      for (int m = 0; m < MR2; ++m)
#pragma unroll
        for (int n = 0; n < 2; ++n){
          int c = col0 + nh*64 + wn*32 + n*16 + (lane & 15);
#pragma unroll
          for (int j = 0; j < 4; ++j){
            int r = row0 + mh*64 + wm*32 + m*16 + (lane >> 4)*4 + j;
            Of[(size_t)r * E_DIM + c] = acc[qd][m][n][j] + bc[nh][n];
          }
        }
    }
  }
#undef MF_Q
}

// ---------------- block-diagonal attention (+fused Wo f32->bf16 cvt) ----------------
#define VSTR 200
#define PSTR 72
#define ATTN_BLKS (H_NUM * NSEG * 3)
__global__ __launch_bounds__(256, 3) void attn_kernel(
    const unsigned short* __restrict__ Q,
    const unsigned short* __restrict__ Kb,
    const unsigned short* __restrict__ V,
    const int* __restrict__ cu,
    unsigned short* __restrict__ O,
    const float* __restrict__ Wo,
    unsigned short* __restrict__ wob,
    int nW4)
{
  __shared__ __align__(16) unsigned short Vt[64*VSTR];     // [d][k-row]
  __shared__ __align__(16) unsigned short Pw[4][16][PSTR]; // per-wave scratch

  const int bid  = blockIdx.x;
  if (bid >= ATTN_BLKS){
    int i = (bid - ATTN_BLKS) * 256 + threadIdx.x;
    if (i < nW4){
      float4 v = reinterpret_cast<const float4*>(Wo)[i];
      ushort4 o;
      o.x = f2bf(v.x); o.y = f2bf(v.y); o.z = f2bf(v.z); o.w = f2bf(v.w);
      reinterpret_cast<ushort4*>(wob)[i] = o;
    }
    return;
  }
  const int unit = bid / 3;
  const int third= bid - unit*3;
  const int h    = unit >> 4;
  const int seg  = unit & 15;
  const int s0   = cu[seg];
  const int L    = cu[seg + 1] - s0;
  if (L <= 0) return;

  const int tid  = threadIdx.x;
  const int lane = tid & 63;
  const int w    = tid >> 6;
  const int row0g = third*64 + w*16;

  const unsigned short* qh = Q  + (size_t)h * S_TOK * D_HEAD;
  const unsigned short* kh = Kb + (size_t)h * S_TOK * D_HEAD;
  const unsigned short* vh = V  + (size_t)h * S_TOK * D_HEAD;

#pragma unroll
  for (int i = 0; i < 6; ++i){
    int task = i*256 + tid;            // 1536 tasks = 192 rows x 8 d-groups
    int sr   = task % 192;
    int grp  = task / 192;
    int svr  = s0 + (sr < L ? sr : L - 1);
    short8 vv = *reinterpret_cast<const short8*>(vh + (size_t)svr*64 + grp*8);
#pragma unroll
    for (int j = 0; j < 8; ++j) Vt[(grp*8 + j)*VSTR + sr] = (unsigned short)vv[j];
  }

  short8 qf[2];
#pragma unroll
  for (int kk = 0; kk < 2; ++kk){
    int r  = row0g + (lane & 15);
    int sr = s0 + (r < L ? r : L - 1);
    qf[kk] = *reinterpret_cast<const short8*>(qh + (size_t)sr*64 + kk*32 + (lane >> 4)*8);
  }

  __syncthreads();

  const f32x4 fz = {0.f, 0.f, 0.f, 0.f};
  const float SCL = 0.125f * 1.44269504088896f;

  f32x4 sacc[12];
#pragma unroll
  for (int nt = 0; nt < 12; ++nt) sacc[nt] = fz;

#pragma unroll
  for (int nt = 0; nt < 12; ++nt){
    int rb = nt*16 + (lane & 15);
    int sr = s0 + (rb < L ? rb : L - 1);
    const unsigned short* kr = kh + (size_t)sr*64 + (lane >> 4)*8;
    short8 kf0 = *reinterpret_cast<const short8*>(kr);
    short8 kf1 = *reinterpret_cast<const short8*>(kr + 32);
    sacc[nt] = __builtin_amdgcn_mfma_f32_16x16x32_bf16(qf[0], kf0, sacc[nt], 0, 0, 0);
    sacc[nt] = __builtin_amdgcn_mfma_f32_16x16x32_bf16(qf[1], kf1, sacc[nt], 0, 0, 0);
  }

  float rinv[4];
#pragma unroll
  for (int j = 0; j < 4; ++j){
    float mx = -1e30f;
#pragma unroll
    for (int nt = 0; nt < 12; ++nt){
      int c = nt*16 + (lane & 15);
      float vv = (c < L) ? sacc[nt][j] : -1e30f;
      sacc[nt][j] = vv;
      mx = fmaxf(mx, vv);
    }
    mx = fmaxf(mx, __shfl_xor(mx, 1, 64));
    mx = fmaxf(mx, __shfl_xor(mx, 2, 64));
    mx = fmaxf(mx, __shfl_xor(mx, 4, 64));
    mx = fmaxf(mx, __shfl_xor(mx, 8, 64));
    float sum = 0.f;
#pragma unroll
    for (int nt = 0; nt < 12; ++nt){
      float pp = exp2f((sacc[nt][j] - mx) * SCL);
      sacc[nt][j] = pp;
      sum += pp;
    }
    sum += __shfl_xor(sum, 1, 64);
    sum += __shfl_xor(sum, 2, 64);
    sum += __shfl_xor(sum, 4, 64);
    sum += __shfl_xor(sum, 8, 64);
    rinv[j] = 1.0f / sum;
  }

  f32x4 oacc[4];
#pragma unroll
  for (int nt = 0; nt < 4; ++nt) oacc[nt] = fz;

#pragma unroll
  for (int kk = 0; kk < 6; ++kk){
#pragma unroll
    for (int ntl = 0; ntl < 2; ++ntl){
      int nt = kk*2 + ntl;
#pragma unroll
      for (int j = 0; j < 4; ++j)
        Pw[w][(lane >> 4)*4 + j][ntl*16 + (lane & 15)] = f2bf(sacc[nt][j]);
    }
    short8 pf = *reinterpret_cast<const short8*>(&Pw[w][lane & 15][(lane >> 4)*8]);
#pragma unroll
    for (int nt4 = 0; nt4 < 4; ++nt4){
      int dcol = nt4*16 + (lane & 15);
      short8 vf = *reinterpret_cast<const short8*>(&Vt[dcol*VSTR + kk*32 + (lane >> 4)*8]);
      oacc[nt4] = __builtin_amdgcn_mfma_f32_16x16x32_bf16(pf, vf, oacc[nt4], 0, 0, 0);
    }
  }

#pragma unroll
  for (int nt4 = 0; nt4 < 4; ++nt4)
#pragma unroll
    for (int j = 0; j < 4; ++j)
      Pw[w][(lane >> 4)*4 + j][nt4*16 + (lane & 15)] = f2bf(oacc[nt4][j] * rinv[j]);

  {
    int r = lane >> 2;
    int gr = row0g + r;
    if (gr < L){
#pragma unroll
      for (int part = 0; part < 2; ++part){
        int c0 = (lane & 3)*16 + part*8;
        short8 vv = *reinterpret_cast<const short8*>(&Pw[w][r][c0]);
        *reinterpret_cast<short8*>(&O[(size_t)(s0 + gr) * E_DIM + h*64 + c0]) = vv;
      }
    }
  }
}

// ---------------- host launch ----------------
extern "C" void kernel_launch(void* const* d_in, const int* in_sizes, int n_in,
                              void* d_out, int out_size, void* d_ws, size_t ws_size,
                              hipStream_t stream)
{
  const float* hs = (const float*)d_in[0];
  const float* Wq = (const float*)d_in[1];
  const float* bq = (const float*)d_in[2];
  const float* Wk = (const float*)d_in[3];
  const float* Wv = (const float*)d_in[4];
  const float* bv = (const float*)d_in[5];
  const float* Wo = (const float*)d_in[6];
  const float* bo = (const float*)d_in[7];
  const int*   cu = (const int*)d_in[8];
  float* out = (float*)d_out;

  unsigned short* p = (unsigned short*)d_ws;
  unsigned short* hsb  = p; p += (size_t)S_TOK * E_DIM;
  unsigned short* wqkv = p; p += (size_t)3 * E_DIM * E_DIM;
  unsigned short* wob  = p; p += (size_t)E_DIM * E_DIM;
  unsigned short* qb   = p; p += (size_t)S_TOK * E_DIM;
  unsigned short* kb   = p; p += (size_t)S_TOK * E_DIM;
  unsigned short* vb   = p; p += (size_t)S_TOK * E_DIM;
  unsigned short* aob  = p; p += (size_t)S_TOK * E_DIM;

  const int nHS4 = S_TOK * E_DIM / 4;
  const int nW4  = E_DIM * E_DIM / 4;
  const int nCvt = nHS4 + 3 * nW4;
  cvt_all<<<(nCvt + 255) / 256, 256, 0, stream>>>(hs, Wq, Wk, Wv, hsb, wqkv, nHS4, nW4);

  // QKV: 12 x 15 = 180 blocks of 512
  gemm_ph<0><<<(S_TOK/256) * (3*E_DIM/256), 512, 0, stream>>>(
      hsb, wqkv, bq, bv, qb, kb, vb, nullptr, S_TOK, 3*E_DIM, E_DIM);

  // attention (960 blocks) + fused Wo conversion
  const int cvtWoBlks = (nW4 + 255) / 256;
  attn_kernel<<<ATTN_BLKS + cvtWoBlks, 256, 0, stream>>>(
      qb, kb, vb, cu, aob, Wo, wob, nW4);

  // out-proj: 24 x 10 = 240 blocks of 256
  gemm_ph<1><<<(S_TOK/128) * (E_DIM/128), 256, 0, stream>>>(
      aob, wob, bo, nullptr, nullptr, nullptr, nullptr, out, S_TOK, E_DIM, E_DIM);
}